// Round 1
// 549.864 us; speedup vs baseline: 1.7982x; 1.7982x over previous
//
#include <hip/hip_runtime.h>

// MeshUnpool — transposed-gather formulation.
//
// R2 gather kernel was request-rate-bound, not BW-bound: 147M scattered 4B
// loads (fb[s0]/fb[s1] at random e, stride-E_OLD layout) = ~215 G req/s with
// only 4 useful bytes per L2 request -> 1.79 TB/s, 22% of peak, VALUBusy 2%.
// FETCH_SIZE 903 MB vs ~206 MB ideal.
//
// Fix: transpose features to featT[b][e][c] (C=128 -> one source column is a
// contiguous 512 B row). Gather then reads whole rows with dwordx4 (fully
// utilized cache lines), applies {w0,w1}, and transposes a [C][JT] tile
// through LDS so the out[b][c][j] stores stay coalesced (256 B segments).
// ~16x fewer memory requests; all traffic streams.
//
// Pipeline:
//   K1 build_map   : per-output-column {s0, s1, w0, w1}        (~9.2 MB ws)
//   K2 transpose   : feat[b][c][e] -> featT[b][e][c]           (ws)
//   K3 gatherT     : out[b][c][j] = w0*featT[b][s0][c] + w1*featT[b][s1][c]
// ws fallback: per-batch featT loop (24.6 MB), else R2 direct gather.

constexpr int B_     = 8;
constexpr int C_     = 128;
constexpr int E_OLD_ = 48000;
constexpr int U_     = 8000;
constexpr int E_NEW_ = E_OLD_ + 3 * U_;          // 72000
constexpr int T_PER_B = U_ + (E_OLD_ - 2 * U_);  // 40000

__device__ __forceinline__ int4 pack_map(int s0, int s1, float w0, float w1) {
    return make_int4(s0, s1, __float_as_int(w0), __float_as_int(w1));
}

// ---------------------------------------------------------------------------
// Kernel 1: build the inverse map. Scattered 16B writes, ~9.2 MB total
// (per-batch target region is 1.15 MB -> coalesces in L2).
__global__ __launch_bounds__(256)
void build_map_kernel(const float* __restrict__ w,
                      const int*   __restrict__ old_idx,
                      const int*   __restrict__ new_idx,
                      const int*   __restrict__ new_left,
                      const int*   __restrict__ new_right,
                      int4*        __restrict__ map) {
    const int b = blockIdx.y;
    const int t = blockIdx.x * blockDim.x + threadIdx.x;
    if (t >= T_PER_B) return;

    int4* mb = map + (size_t)b * E_NEW_;

    if (t < U_) {
        const int u   = t;
        const int jl  = old_idx [b * E_OLD_ + u];
        const int jr  = old_idx [b * E_OLD_ + U_ + u];
        const int jn  = new_idx [b * U_ + u];
        const int jnl = new_left [b * U_ + u];
        const int jnr = new_right[b * U_ + u];

        const float* wp = w + ((size_t)b * U_ + u) * 6;
        const float lw0 = wp[0], lw1 = wp[1], lw2 = wp[2];
        const float rw0 = wp[3], rw1 = wp[4], rw2 = wp[5];

        mb[jl]  = pack_map(u,       u,       lw0,        0.f);
        mb[jnl] = pack_map(u,       u,       lw1,        0.f);
        mb[jr]  = pack_map(U_ + u,  U_ + u,  rw0,        0.f);
        mb[jnr] = pack_map(U_ + u,  U_ + u,  rw1,        0.f);
        mb[jn]  = pack_map(u,       U_ + u,  0.5f * lw2, 0.5f * rw2);
    } else {
        const int e = t + U_;  // [2U, E_OLD)
        const int j = old_idx[b * E_OLD_ + e];
        mb[j] = pack_map(e, e, 1.0f, 0.f);
    }
}

// ---------------------------------------------------------------------------
// Kernel 2: 32x32 LDS-tiled transpose feat[b][c][e] -> featT[bl][e][c].
// Both sides coalesced; +1 pad kills LDS bank conflicts.
constexpr int TT = 32;

__global__ __launch_bounds__(256)
void transpose_kernel(const float* __restrict__ feat,
                      float*       __restrict__ featT,
                      int b0) {
    __shared__ float tile[TT][TT + 1];
    const int bl = blockIdx.z;          // local batch (featT index)
    const int b  = b0 + bl;             // global batch (feat index)
    const int e0 = blockIdx.x * TT;
    const int c0 = blockIdx.y * TT;
    const int tx = threadIdx.x;         // 0..31 (e within tile on read)
    const int ty = threadIdx.y;         // 0..7

    const float* fb = feat + (size_t)b * C_ * E_OLD_;
    #pragma unroll
    for (int i = 0; i < 4; ++i) {
        const int c = c0 + ty + 8 * i;
        tile[ty + 8 * i][tx] = fb[(size_t)c * E_OLD_ + e0 + tx];
    }
    __syncthreads();
    float* ft = featT + (size_t)bl * E_OLD_ * C_;
    #pragma unroll
    for (int i = 0; i < 4; ++i) {
        const int e = e0 + ty + 8 * i;
        ft[(size_t)e * C_ + c0 + tx] = tile[tx][ty + 8 * i];
    }
}

// ---------------------------------------------------------------------------
// Kernel 3: transposed gather. Block = 256 threads, tile = 64 output columns
// x 128 channels.
// Phase A: 4 threads per column j; thread (j, cq) reads featT[s0][cq*32..+31]
//          as 8x dwordx4 (contiguous 128 B per thread, full-line requests),
//          FMAs w0/w1 (second row read skipped when w1==0 -> only U of E_NEW
//          columns pay 2 rows), stages into LDS tile[j][c].
// Phase B: thread (j, cg) reads tile[j][cg*32..+31], stores out[b][c][j0+j];
//          per store instruction lanes span j=0..63 -> 256 B coalesced
//          segments (j0*4 is 256B-aligned: JT=64).
constexpr int JT = 64;
constexpr int TILES_PER_B = E_NEW_ / JT;   // 1125 exactly, no tail

__global__ __launch_bounds__(256)
void gatherT_kernel(const float* __restrict__ featT,
                    const int4*  __restrict__ map,
                    float*       __restrict__ out,
                    int b0, int nb) {
    __shared__ float tile[JT][C_ + 4];     // 64*132*4 = 33.8 KB -> 4 blocks/CU
    const int bl    = blockIdx.x % nb;     // local batch (featT index)
    const int b     = b0 + bl;             // global batch (map/out index)
    const int chunk = blockIdx.x / nb;
    const int j0    = chunk * JT;
    const int t     = threadIdx.x;

    // ---- Phase A: gather rows -> LDS tile --------------------------------
    {
        const int j  = t >> 2;             // 0..63
        const int cq = t & 3;              // 0..3  (c-quadrant of 32)
        const int4 m = map[(size_t)b * E_NEW_ + j0 + j];
        const float w0 = __int_as_float(m.z);
        const float w1 = __int_as_float(m.w);

        const float* fTb = featT + (size_t)bl * E_OLD_ * C_;
        const float4* r0 = (const float4*)(fTb + (size_t)m.x * C_) + cq * 8;

        float4 acc[8];
        #pragma unroll
        for (int i = 0; i < 8; ++i) {
            const float4 f = r0[i];
            acc[i].x = w0 * f.x;
            acc[i].y = w0 * f.y;
            acc[i].z = w0 * f.z;
            acc[i].w = w0 * f.w;
        }
        if (w1 != 0.f) {                   // only U of E_NEW columns (11%)
            const float4* r1 = (const float4*)(fTb + (size_t)m.y * C_) + cq * 8;
            #pragma unroll
            for (int i = 0; i < 8; ++i) {
                const float4 f = r1[i];
                acc[i].x += w1 * f.x;
                acc[i].y += w1 * f.y;
                acc[i].z += w1 * f.z;
                acc[i].w += w1 * f.w;
            }
        }
        float* trow = &tile[j][cq * 32];   // row stride 132 floats = 528 B (16B-aligned)
        #pragma unroll
        for (int i = 0; i < 8; ++i) {
            *(float4*)(trow + 4 * i) = acc[i];
        }
    }
    __syncthreads();

    // ---- Phase B: LDS tile -> coalesced global stores --------------------
    {
        const int j  = t & 63;             // 0..63
        const int cg = t >> 6;             // 0..3
        const float* trow = &tile[j][cg * 32];
        float* ob = out + (size_t)b * C_ * E_NEW_
                        + (size_t)(cg * 32) * E_NEW_ + j0 + j;
        #pragma unroll
        for (int k4 = 0; k4 < 8; ++k4) {
            const float4 v = *(const float4*)(trow + 4 * k4);
            ob[(size_t)(4 * k4 + 0) * E_NEW_] = v.x;
            ob[(size_t)(4 * k4 + 1) * E_NEW_] = v.y;
            ob[(size_t)(4 * k4 + 2) * E_NEW_] = v.z;
            ob[(size_t)(4 * k4 + 3) * E_NEW_] = v.w;
        }
    }
}

// ---------------------------------------------------------------------------
// Fallback (R2 kernel): direct strided gather, used only if ws is too small
// for even a single-batch featT.
constexpr int K2_BLOCK     = 256;
constexpr int CHUNKS_PER_B = (E_NEW_ + K2_BLOCK - 1) / K2_BLOCK;  // 282

__global__ __launch_bounds__(K2_BLOCK)
void gather_kernel(const float* __restrict__ feat,
                   const int4*  __restrict__ map,
                   float*       __restrict__ out) {
    const int b     = blockIdx.x % B_;
    const int chunk = blockIdx.x / B_;
    const int j     = chunk * K2_BLOCK + threadIdx.x;
    if (j >= E_NEW_) return;

    const int4 m  = map[(size_t)b * E_NEW_ + j];
    const int  s0 = m.x;
    const int  s1 = m.y;
    const float w0 = __int_as_float(m.z);
    const float w1 = __int_as_float(m.w);

    const float* fb = feat + (size_t)b * C_ * E_OLD_;
    float*       ob = out  + (size_t)b * C_ * E_NEW_ + j;

    #pragma unroll 4
    for (int c = 0; c < C_; ++c) {
        const float f0 = fb[s0];
        const float f1 = fb[s1];
        *ob = w0 * f0 + w1 * f1;
        fb += E_OLD_;
        ob += E_NEW_;
    }
}

// ---------------------------------------------------------------------------
extern "C" void kernel_launch(void* const* d_in, const int* in_sizes, int n_in,
                              void* d_out, int out_size, void* d_ws, size_t ws_size,
                              hipStream_t stream) {
    const float* feat      = (const float*)d_in[0];
    const float* w         = (const float*)d_in[1];
    const int*   old_idx   = (const int*)  d_in[2];
    // d_in[3] = left_idx  (== old_idx[:, :U])   — unused
    // d_in[4] = right_idx (== old_idx[:, U:2U]) — unused
    const int*   new_idx   = (const int*)  d_in[5];
    const int*   new_left  = (const int*)  d_in[6];
    const int*   new_right = (const int*)  d_in[7];
    float*       out       = (float*)d_out;

    int4* map = (int4*)d_ws;                                   // 9.216 MB
    const size_t map_bytes = (size_t)B_ * E_NEW_ * sizeof(int4);
    const size_t featT_off = (map_bytes + 255) & ~(size_t)255;
    const size_t featT_one = (size_t)E_OLD_ * C_ * sizeof(float);   // 24.58 MB
    const size_t featT_all = (size_t)B_ * featT_one;                // 196.6 MB
    float* featT = (float*)((char*)d_ws + featT_off);

    {
        dim3 block(256);
        dim3 grid((T_PER_B + 255) / 256, B_);
        build_map_kernel<<<grid, block, 0, stream>>>(
            w, old_idx, new_idx, new_left, new_right, map);
    }

    if (ws_size >= featT_off + featT_all) {
        // Full-batch path: one transpose, one gather.
        {
            dim3 block(32, 8);
            dim3 grid(E_OLD_ / TT, C_ / TT, B_);
            transpose_kernel<<<grid, block, 0, stream>>>(feat, featT, 0);
        }
        {
            dim3 block(256);
            dim3 grid(TILES_PER_B * B_);
            gatherT_kernel<<<grid, block, 0, stream>>>(featT, map, out, 0, B_);
        }
    } else if (ws_size >= featT_off + featT_one) {
        // Per-batch loop reusing one featT slab (stream-serialized).
        for (int b = 0; b < B_; ++b) {
            dim3 tblock(32, 8);
            dim3 tgrid(E_OLD_ / TT, C_ / TT, 1);
            transpose_kernel<<<tgrid, tblock, 0, stream>>>(feat, featT, b);
            dim3 gblock(256);
            dim3 ggrid(TILES_PER_B);
            gatherT_kernel<<<ggrid, gblock, 0, stream>>>(featT, map, out, b, 1);
        }
    } else {
        // Workspace too small for any featT: R2 direct gather.
        dim3 block(K2_BLOCK);
        dim3 grid(CHUNKS_PER_B * B_);
        gather_kernel<<<grid, block, 0, stream>>>(feat, map, out);
    }
}